// Round 6
// baseline (918.774 us; speedup 1.0000x reference)
//
#include <hip/hip_runtime.h>

#define NN 100000
#define NE 1600000
#define FEAT 128
#define NGRAPH 128
#define BSHIFT 9
#define NB 196          // ceil(NN / 512)
#define NCHUNK 400
#define CHUNK 4000      // NE / NCHUNK exactly

typedef __attribute__((ext_vector_type(8))) short bf16x8;
typedef __attribute__((ext_vector_type(4))) float f32x4;

__device__ __forceinline__ unsigned short f2bf(float f) {
    unsigned u = __float_as_uint(f);
    return (unsigned short)((u + 0x7fffu + ((u >> 16) & 1u)) >> 16);  // RNE
}
__device__ __forceinline__ float bf2f(unsigned short h) {
    return __uint_as_float(((unsigned)h) << 16);
}

// ==================== W hi/lo split prep ====================
__global__ __launch_bounds__(256)
void wsplit_kernel(const float* __restrict__ W, short* __restrict__ Wh,
                   short* __restrict__ Wl, int n)
{
    int i = blockIdx.x * 256 + threadIdx.x;
    if (i < n) {
        float f = W[i];
        unsigned short h = f2bf(f);
        Wh[i] = (short)h;
        Wl[i] = (short)f2bf(f - bf2f(h));
    }
}

// ==================== radix-partition CSR build ====================
__global__ __launch_bounds__(256)
void p1a_count(const int* __restrict__ ei, int* __restrict__ cnt_T)
{
    __shared__ int hist[NB];
    const int b = blockIdx.x, tid = threadIdx.x;
    for (int i = tid; i < NB; i += 256) hist[i] = 0;
    __syncthreads();
    const int e0 = b * CHUNK;
    for (int e = e0 + tid; e < e0 + CHUNK; e += 256)
        atomicAdd(&hist[ei[NE + e] >> BSHIFT], 1);
    __syncthreads();
    for (int k = tid; k < NB; k += 256) cnt_T[k * NCHUNK + b] = hist[k];
}

__global__ __launch_bounds__(1024)
void scan1_kernel(const int* __restrict__ in, int* __restrict__ out,
                  int* __restrict__ bsum, int n)
{
    __shared__ int sh[1024];
    const int tid = threadIdx.x;
    const int gid = blockIdx.x * 1024 + tid;
    int v = (gid < n) ? in[gid] : 0;
    sh[tid] = v;
    __syncthreads();
    #pragma unroll
    for (int d = 1; d < 1024; d <<= 1) {
        int t = (tid >= d) ? sh[tid - d] : 0;
        __syncthreads();
        sh[tid] += t;
        __syncthreads();
    }
    if (gid < n) out[gid] = sh[tid] - v;
    if (tid == 1023) bsum[blockIdx.x] = sh[1023];
}

__global__ __launch_bounds__(128)
void scan2_kernel(int* __restrict__ bsum, int nb)
{
    __shared__ int sh[128];
    const int tid = threadIdx.x;
    int v = (tid < nb) ? bsum[tid] : 0;
    sh[tid] = v;
    __syncthreads();
    #pragma unroll
    for (int d = 1; d < 128; d <<= 1) {
        int t = (tid >= d) ? sh[tid - d] : 0;
        __syncthreads();
        sh[tid] += t;
        __syncthreads();
    }
    if (tid < nb) bsum[tid] = sh[tid] - v;
}

__global__ __launch_bounds__(1024)
void scan3g_kernel(int* __restrict__ arr, const int* __restrict__ bsum, int n)
{
    const int gid = blockIdx.x * 1024 + threadIdx.x;
    if (gid < n) arr[gid] += bsum[blockIdx.x];
}

__global__ __launch_bounds__(256)
void p1b_scatter(const int* __restrict__ ei, const int* __restrict__ offs_T,
                 int2* __restrict__ ebuf)
{
    __shared__ int cur[NB];
    const int b = blockIdx.x, tid = threadIdx.x;
    for (int i = tid; i < NB; i += 256) cur[i] = offs_T[i * NCHUNK + b];
    __syncthreads();
    const int e0 = b * CHUNK;
    for (int e = e0 + tid; e < e0 + CHUNK; e += 256) {
        int s = ei[e], d = ei[NE + e];
        int pos = atomicAdd(&cur[d >> BSHIFT], 1);
        ebuf[pos] = make_int2(s, d);
    }
}

__global__ __launch_bounds__(512)
void p2_csr(const int2* __restrict__ ebuf, const int* __restrict__ offs_T,
            int* __restrict__ off, int* __restrict__ csr)
{
    __shared__ int degc[512];
    __shared__ int sh[512];
    const int k = blockIdx.x, tid = threadIdx.x;
    const int base = k << BSHIFT;
    const int bs = offs_T[k * NCHUNK];
    const int be = (k == NB - 1) ? NE : offs_T[(k + 1) * NCHUNK];
    degc[tid] = 0;
    __syncthreads();
    for (int e = bs + tid; e < be; e += 512)
        atomicAdd(&degc[ebuf[e].y - base], 1);
    __syncthreads();
    int v = degc[tid];
    sh[tid] = v;
    __syncthreads();
    #pragma unroll
    for (int d = 1; d < 512; d <<= 1) {
        int t = (tid >= d) ? sh[tid - d] : 0;
        __syncthreads();
        sh[tid] += t;
        __syncthreads();
    }
    const int excl = bs + sh[tid] - v;
    const int n = base + tid;
    if (n <= NN) off[n] = excl;
    degc[tid] = excl;
    __syncthreads();
    for (int e = bs + tid; e < be; e += 512) {
        int2 p = ebuf[e];
        int slot = atomicAdd(&degc[p.y - base], 1);
        csr[slot] = p.x;
    }
}

// ==================== aggregation: x_eff = (h + sum_in h[src]) * 0.5 + h ====================
__global__ __launch_bounds__(256)
void aggregate_kernel(const float* __restrict__ h, const int* __restrict__ off,
                      const int* __restrict__ csr, float* __restrict__ xeff, int nn)
{
    const int node = blockIdx.x * 4 + (threadIdx.x >> 6);
    if (node >= nn) return;
    const int lane = threadIdx.x & 63;
    const int s = off[node], e = off[node + 1];
    float2 acc = make_float2(0.f, 0.f);
    for (int base = s; base < e; base += 64) {
        const int cnt = min(64, e - base);
        int src_l = (base + lane < e) ? csr[base + lane] : 0;
        int j = 0;
        for (; j + 4 <= cnt; j += 4) {
            int s0 = __shfl(src_l, j + 0);
            int s1 = __shfl(src_l, j + 1);
            int s2 = __shfl(src_l, j + 2);
            int s3 = __shfl(src_l, j + 3);
            float2 v0 = reinterpret_cast<const float2*>(h + (size_t)s0 * FEAT)[lane];
            float2 v1 = reinterpret_cast<const float2*>(h + (size_t)s1 * FEAT)[lane];
            float2 v2 = reinterpret_cast<const float2*>(h + (size_t)s2 * FEAT)[lane];
            float2 v3 = reinterpret_cast<const float2*>(h + (size_t)s3 * FEAT)[lane];
            acc.x += v0.x + v1.x + v2.x + v3.x;
            acc.y += v0.y + v1.y + v2.y + v3.y;
        }
        for (; j < cnt; ++j) {
            int sj = __shfl(src_l, j);
            float2 v = reinterpret_cast<const float2*>(h + (size_t)sj * FEAT)[lane];
            acc.x += v.x; acc.y += v.y;
        }
    }
    float2 hv = reinterpret_cast<const float2*>(h + (size_t)node * FEAT)[lane];
    float2 o;
    o.x = (hv.x + acc.x) * 0.5f + hv.x;
    o.y = (hv.y + acc.y) * 0.5f + hv.y;
    reinterpret_cast<float2*>(xeff + (size_t)node * FEAT)[lane] = o;
}

// ==================== MFMA split-bf16 GEMM: out = relu(A @ W^T + b) ====================
// C = Ah*Wh + Al*Wh + Ah*Wl  (Al*Wl ~2^-18 rel, dropped).
// Block: 128 rows x 128 cols, 4 waves; wave w owns rows [w*32, w*32+32).
// LDS: A hi/lo bf16, row-major [128][128], XOR-swizzled ((r&7)<<3 on ushort idx).
__global__ __launch_bounds__(256, 2)
void gemm_mfma_kernel(const float* __restrict__ A, const short* __restrict__ Wh,
                      const short* __restrict__ Wl, const float* __restrict__ bias,
                      float* __restrict__ out, int n_nodes)
{
    __shared__ short aHi[128 * 128];   // 32 KB
    __shared__ short aLo[128 * 128];   // 32 KB
    const int tid = threadIdx.x;
    const int row0 = blockIdx.x * 128;

    // stage + split A: thread -> (row r = tid>>1, k-half = (tid&1)*64)
    {
        const int r = tid >> 1;
        const int kh = (tid & 1) << 6;
        const int n = row0 + r;
        const int swz = (r & 7) << 3;
        if (n < n_nodes) {
            const float* ar = A + (size_t)n * FEAT + kh;
            #pragma unroll
            for (int i = 0; i < 8; ++i) {
                int k = i * 8;
                float4 f0 = *reinterpret_cast<const float4*>(ar + k);
                float4 f1 = *reinterpret_cast<const float4*>(ar + k + 4);
                float fv[8] = {f0.x, f0.y, f0.z, f0.w, f1.x, f1.y, f1.z, f1.w};
                bf16x8 h8, l8;
                #pragma unroll
                for (int j = 0; j < 8; ++j) {
                    unsigned short h = f2bf(fv[j]);
                    h8[j] = (short)h;
                    l8[j] = (short)f2bf(fv[j] - bf2f(h));
                }
                int idx = (r * 128 + kh + k) ^ swz;
                *reinterpret_cast<bf16x8*>(&aHi[idx]) = h8;
                *reinterpret_cast<bf16x8*>(&aLo[idx]) = l8;
            }
        } else {
            bf16x8 z = {};
            #pragma unroll
            for (int i = 0; i < 8; ++i) {
                int idx = (r * 128 + kh + i * 8) ^ swz;
                *reinterpret_cast<bf16x8*>(&aHi[idx]) = z;
                *reinterpret_cast<bf16x8*>(&aLo[idx]) = z;
            }
        }
    }
    __syncthreads();

    const int lane = tid & 63;
    const int w = tid >> 6;
    const int lr = lane & 15;          // A-row / B-col within tile
    const int lk = (lane >> 4) << 3;   // k sub-offset within 32-chunk

    f32x4 acc[2][8] = {};
    for (int kc = 0; kc < 4; ++kc) {
        const int kf = kc * 32 + lk;
        bf16x8 bh[8], bl[8];
        #pragma unroll
        for (int ct = 0; ct < 8; ++ct) {
            const int o = ct * 16 + lr;
            bh[ct] = *reinterpret_cast<const bf16x8*>(&Wh[o * 128 + kf]);
            bl[ct] = *reinterpret_cast<const bf16x8*>(&Wl[o * 128 + kf]);
        }
        #pragma unroll
        for (int rt = 0; rt < 2; ++rt) {
            const int rr = (w << 5) + (rt << 4) + lr;
            const int idx = (rr * 128 + kf) ^ ((rr & 7) << 3);
            bf16x8 ah = *reinterpret_cast<const bf16x8*>(&aHi[idx]);
            bf16x8 al = *reinterpret_cast<const bf16x8*>(&aLo[idx]);
            #pragma unroll
            for (int ct = 0; ct < 8; ++ct) {
                acc[rt][ct] = __builtin_amdgcn_mfma_f32_16x16x32_bf16(ah, bh[ct], acc[rt][ct], 0, 0, 0);
                acc[rt][ct] = __builtin_amdgcn_mfma_f32_16x16x32_bf16(al, bh[ct], acc[rt][ct], 0, 0, 0);
                acc[rt][ct] = __builtin_amdgcn_mfma_f32_16x16x32_bf16(ah, bl[ct], acc[rt][ct], 0, 0, 0);
            }
        }
    }

    // epilogue: C col = lane&15, row = (lane>>4)*4 + j  (m89-verified)
    #pragma unroll
    for (int rt = 0; rt < 2; ++rt) {
        const int rbase = row0 + (w << 5) + (rt << 4) + ((lane >> 4) << 2);
        #pragma unroll
        for (int ct = 0; ct < 8; ++ct) {
            const int col = ct * 16 + lr;
            const float b = bias[col];
            #pragma unroll
            for (int j = 0; j < 4; ++j) {
                const int n = rbase + j;
                if (n < n_nodes)
                    out[(size_t)n * FEAT + col] = fmaxf(acc[rt][ct][j] + b, 0.f);
            }
        }
    }
}

// ==================== legacy vector GEMM (fallback path only) ====================
__global__ __launch_bounds__(256, 2)
void gemm_relu_kernel(const float* __restrict__ A, const float* __restrict__ W,
                      const float* __restrict__ bias, float* __restrict__ out, int n_nodes)
{
    __shared__ float xt[64][128];
    __shared__ float wt[64][128];
    const int tid = threadIdx.x;
    const int row0 = blockIdx.x * 128;
    const int r  = tid >> 1;
    const int ks = (tid & 1) << 5;
    const int tn = (tid >> 4) << 3;
    const int to = (tid & 15) << 3;
    float acc[8][8] = {};

    for (int c = 0; c < 2; ++c) {
        const int k0 = c * 64;
        {
            const float4* wrow = reinterpret_cast<const float4*>(W + r * FEAT + k0 + ks);
            #pragma unroll
            for (int i = 0; i < 8; ++i) {
                float4 w4 = wrow[i];
                int kk = ks + i * 4;
                wt[kk + 0][r] = w4.x; wt[kk + 1][r] = w4.y;
                wt[kk + 2][r] = w4.z; wt[kk + 3][r] = w4.w;
            }
        }
        {
            const int n = row0 + r;
            if (n < n_nodes) {
                const float4* ar = reinterpret_cast<const float4*>(A + (size_t)n * FEAT + k0 + ks);
                #pragma unroll
                for (int i = 0; i < 8; ++i) {
                    float4 a4 = ar[i];
                    int kk = ks + i * 4;
                    xt[kk + 0][r] = a4.x; xt[kk + 1][r] = a4.y;
                    xt[kk + 2][r] = a4.z; xt[kk + 3][r] = a4.w;
                }
            } else {
                #pragma unroll
                for (int i = 0; i < 8; ++i) {
                    int kk = ks + i * 4;
                    xt[kk + 0][r] = 0.f; xt[kk + 1][r] = 0.f;
                    xt[kk + 2][r] = 0.f; xt[kk + 3][r] = 0.f;
                }
            }
        }
        __syncthreads();
        #pragma unroll 4
        for (int k = 0; k < 64; ++k) {
            float4 x0 = *reinterpret_cast<const float4*>(&xt[k][tn]);
            float4 x1 = *reinterpret_cast<const float4*>(&xt[k][tn + 4]);
            float4 w0 = *reinterpret_cast<const float4*>(&wt[k][to]);
            float4 w1 = *reinterpret_cast<const float4*>(&wt[k][to + 4]);
            float xv[8] = {x0.x, x0.y, x0.z, x0.w, x1.x, x1.y, x1.z, x1.w};
            float wv[8] = {w0.x, w0.y, w0.z, w0.w, w1.x, w1.y, w1.z, w1.w};
            #pragma unroll
            for (int i = 0; i < 8; ++i)
                #pragma unroll
                for (int j = 0; j < 8; ++j)
                    acc[i][j] = fmaf(xv[i], wv[j], acc[i][j]);
        }
        __syncthreads();
    }

    float bv[8];
    #pragma unroll
    for (int j = 0; j < 8; ++j) bv[j] = bias[to + j];
    #pragma unroll
    for (int i = 0; i < 8; ++i) {
        int n = row0 + tn + i;
        if (n >= n_nodes) break;
        float4 o0, o1;
        o0.x = fmaxf(acc[i][0] + bv[0], 0.f);
        o0.y = fmaxf(acc[i][1] + bv[1], 0.f);
        o0.z = fmaxf(acc[i][2] + bv[2], 0.f);
        o0.w = fmaxf(acc[i][3] + bv[3], 0.f);
        o1.x = fmaxf(acc[i][4] + bv[4], 0.f);
        o1.y = fmaxf(acc[i][5] + bv[5], 0.f);
        o1.z = fmaxf(acc[i][6] + bv[6], 0.f);
        o1.w = fmaxf(acc[i][7] + bv[7], 0.f);
        float* op = out + (size_t)n * FEAT + to;
        *reinterpret_cast<float4*>(op) = o0;
        *reinterpret_cast<float4*>(op + 4) = o1;
    }
}

// ==================== pooling ====================
__global__ __launch_bounds__(512)
void pool_kernel(const float* __restrict__ y, const int* __restrict__ batch,
                 float* __restrict__ out, int n_nodes, int layer)
{
    const int g = blockIdx.x;
    int lo = 0, hi = n_nodes;
    while (lo < hi) { int mid = (lo + hi) >> 1; if (batch[mid] < g) lo = mid + 1; else hi = mid; }
    const int start = lo;
    hi = n_nodes;
    while (lo < hi) { int mid = (lo + hi) >> 1; if (batch[mid] < g + 1) lo = mid + 1; else hi = mid; }
    const int end = lo;

    const int tid = threadIdx.x;
    const int f = tid & 127;
    const int q = tid >> 7;
    float sum = 0.f;
    for (int n = start + q; n < end; n += 4)
        sum += y[(size_t)n * FEAT + f];

    __shared__ float red[512];
    red[tid] = sum;
    __syncthreads();
    if (tid < 128)
        out[g * (3 * FEAT) + layer * FEAT + tid]
            = red[tid] + red[tid + 128] + red[tid + 256] + red[tid + 384];
}

// ==================== fallback (ws too small): atomic scatter ====================
__global__ __launch_bounds__(256)
void scatter_kernel(const float* __restrict__ h, const int* __restrict__ ei,
                    float* __restrict__ agg, int n_edges)
{
    int e = blockIdx.x * 4 + (threadIdx.x >> 6);
    if (e >= n_edges) return;
    int lane = threadIdx.x & 63;
    int s = ei[e];
    int d = ei[n_edges + e];
    float2 v = reinterpret_cast<const float2*>(h + (size_t)s * FEAT)[lane];
    float* ap = agg + (size_t)d * FEAT + lane * 2;
    atomicAdd(ap, v.x);
    atomicAdd(ap + 1, v.y);
}

__global__ __launch_bounds__(256)
void combine_kernel(const float* __restrict__ h, float* __restrict__ agg_xeff, size_t n4)
{
    size_t i = (size_t)blockIdx.x * 256 + threadIdx.x;
    if (i >= n4) return;
    float4 a = reinterpret_cast<const float4*>(h)[i];
    float4 g = reinterpret_cast<float4*>(agg_xeff)[i];
    float4 o;
    o.x = (a.x + g.x) * 0.5f + a.x;
    o.y = (a.y + g.y) * 0.5f + a.y;
    o.z = (a.z + g.z) * 0.5f + a.z;
    o.w = (a.w + g.w) * 0.5f + a.w;
    reinterpret_cast<float4*>(agg_xeff)[i] = o;
}

extern "C" void kernel_launch(void* const* d_in, const int* in_sizes, int n_in,
                              void* d_out, int out_size, void* d_ws, size_t ws_size,
                              hipStream_t stream)
{
    const float* x     = (const float*)d_in[0];
    const int*   ei    = (const int*)d_in[1];
    const int*   batch = (const int*)d_in[2];
    const float* W1[3] = {(const float*)d_in[4], (const float*)d_in[8],  (const float*)d_in[12]};
    const float* b1[3] = {(const float*)d_in[5], (const float*)d_in[9],  (const float*)d_in[13]};
    const float* W2[3] = {(const float*)d_in[6], (const float*)d_in[10], (const float*)d_in[14]};
    const float* b2[3] = {(const float*)d_in[7], (const float*)d_in[11], (const float*)d_in[15]};

    const size_t nf = (size_t)NN * FEAT;
    float* bufA = (float*)d_ws;        // x_eff  (aliased: scan transients during build)
    float* bufB = bufA + nf;           // h1     (aliased: ebuf during build)
    float* bufC = bufB + nf;           // layer output
    float* outp = (float*)d_out;
    const int gemm_grid = (NN + 127) / 128;

    const int M = NB * NCHUNK;                       // 78400
    const int scanM_blocks = (M + 1023) / 1024;      // 77
    const int WN = FEAT * FEAT;                      // 16384

    const size_t need_full = 3 * nf * 4 + (size_t)(NN + 1 + NE) * 4 + (size_t)12 * WN * 2;

    if (ws_size >= need_full) {
        int* off      = (int*)(bufC + nf);     // NN+1
        int* csr      = off + (NN + 1);        // NE
        short* wbase  = (short*)(csr + NE);    // 12 * WN shorts
        short* wh[6], * wl[6];
        for (int i = 0; i < 6; ++i) { wh[i] = wbase + i * WN; wl[i] = wbase + (6 + i) * WN; }
        // transients aliased into bufA / bufB
        int* cnt_T  = (int*)bufA;
        int* offs_T = cnt_T + M;
        int* bsum   = offs_T + M;
        int2* ebuf  = (int2*)bufB;

        // W splits (order: W1_l0, W2_l0, W1_l1, W2_l1, W1_l2, W2_l2)
        const float* Ws[6] = {W1[0], W2[0], W1[1], W2[1], W1[2], W2[2]};
        for (int i = 0; i < 6; ++i)
            wsplit_kernel<<<(WN + 255) / 256, 256, 0, stream>>>(Ws[i], wh[i], wl[i], WN);

        p1a_count<<<NCHUNK, 256, 0, stream>>>(ei, cnt_T);
        scan1_kernel<<<scanM_blocks, 1024, 0, stream>>>(cnt_T, offs_T, bsum, M);
        scan2_kernel<<<1, 128, 0, stream>>>(bsum, scanM_blocks);
        scan3g_kernel<<<scanM_blocks, 1024, 0, stream>>>(offs_T, bsum, M);
        p1b_scatter<<<NCHUNK, 256, 0, stream>>>(ei, offs_T, ebuf);
        p2_csr<<<NB, 512, 0, stream>>>(ebuf, offs_T, off, csr);

        const float* h = x;
        for (int l = 0; l < 3; ++l) {
            aggregate_kernel<<<(NN + 3) / 4, 256, 0, stream>>>(h, off, csr, bufA, NN);
            gemm_mfma_kernel<<<gemm_grid, 256, 0, stream>>>(bufA, wh[2 * l], wl[2 * l], b1[l], bufB, NN);
            gemm_mfma_kernel<<<gemm_grid, 256, 0, stream>>>(bufB, wh[2 * l + 1], wl[2 * l + 1], b2[l], bufC, NN);
            pool_kernel<<<NGRAPH, 512, 0, stream>>>(bufC, batch, outp, NN, l);
            h = bufC;
        }
    } else if (ws_size >= 3 * nf * 4) {
        const float* h = x;
        for (int l = 0; l < 3; ++l) {
            hipMemsetAsync(bufA, 0, nf * 4, stream);
            scatter_kernel<<<(NE + 3) / 4, 256, 0, stream>>>(h, ei, bufA, NE);
            combine_kernel<<<(int)((nf / 4 + 255) / 256), 256, 0, stream>>>(h, bufA, nf / 4);
            gemm_relu_kernel<<<gemm_grid, 256, 0, stream>>>(bufA, W1[l], b1[l], bufB, NN);
            gemm_relu_kernel<<<gemm_grid, 256, 0, stream>>>(bufB, W2[l], b2[l], bufC, NN);
            pool_kernel<<<NGRAPH, 512, 0, stream>>>(bufC, batch, outp, NN, l);
            h = bufC;
        }
    }
}